// Round 14
// baseline (91.352 us; speedup 1.0000x reference)
//
#include <hip/hip_runtime.h>
#include <math.h>

#define N_DIM 64
#define C_DIM 512
#define K_DIM 64
#define P_DIM 900
#define P_PAD 928          // 29 * 32 (agg K-steps of 32)
#define PTILES 15          // p-blocks of 64
#define CTILES 8           // c-blocks of 64 (transpose)

typedef __attribute__((ext_vector_type(8))) short short8;   // 8 bf16 = 4 VGPR
typedef __attribute__((ext_vector_type(4))) float f32x4;    // MFMA C/D + x loads
typedef __attribute__((ext_vector_type(4))) uint  u32x4;

#define A2_ELEMS   ((size_t)N_DIM * K_DIM * P_PAD)
#define ASUM_ELEMS ((size_t)N_DIM * K_DIM * PTILES)
#define SSQ_ELEMS  ((size_t)CTILES * N_DIM * P_DIM)
#define XTF_ELEMS  ((size_t)N_DIM * PTILES * 16 * 4 * 64 * 8)   // 63 MB bf16

// fp32 -> bf16 bits, round-to-nearest-even (inputs finite)
__device__ inline ushort f2bf(float f) {
  uint u = __builtin_bit_cast(uint, f);
  u += 0x7FFFu + ((u >> 16) & 1u);
  return (ushort)(u >> 16);
}
__device__ inline uint pk2(float a, float b) {
  return (uint)f2bf(a) | ((uint)f2bf(b) << 16);
}

// ---------------------------------------------------------------------------
// Kernel T: transpose x[n][c][p] fp32 -> xtf bf16 in ASSIGN-FRAGMENT ORDER:
// xtf[((n*15+pt)*16 + ks)*4 + lhi][p_local 0..63][8 c]  (c = ks*32+lhi*8+j).
// Also ssq_part[ct][n][p] = sum of x^2 over this ctile's 64 channels.
// Reads: float4 along p (256B segments). Writes: 64 lanes x 16B = 1KB runs.
// Pad pixels (p>=900, last ptile) are zero-filled.
// ---------------------------------------------------------------------------
__global__ __launch_bounds__(256) void transpose_x(
    const float* __restrict__ x, ushort* __restrict__ xtf,
    float* __restrict__ ssq_part)
{
  const int ct = blockIdx.x, pt = blockIdx.y, n = blockIdx.z;
  const int p0 = pt * 64, c0 = ct * 64, tid = threadIdx.x;
  __shared__ float lds[64][68];      // [c_local][p_local], pad 68
  __shared__ float red[4][64];

  const float* xb = x + ((size_t)n * C_DIM + c0) * P_DIM;
  const int cl = tid >> 4;           // 0..15
  const int p4 = (tid & 15) * 4;     // 0..60
#pragma unroll
  for (int pass = 0; pass < 4; ++pass) {
    const int c = cl + pass * 16;
    const int gp = p0 + p4;
    float4 v;
    if (gp + 4 <= P_DIM) {
      v = *(const float4*)(xb + (size_t)c * P_DIM + gp);
    } else {
      v.x = (gp + 0 < P_DIM) ? xb[(size_t)c * P_DIM + gp + 0] : 0.f;
      v.y = (gp + 1 < P_DIM) ? xb[(size_t)c * P_DIM + gp + 1] : 0.f;
      v.z = (gp + 2 < P_DIM) ? xb[(size_t)c * P_DIM + gp + 2] : 0.f;
      v.w = (gp + 3 < P_DIM) ? xb[(size_t)c * P_DIM + gp + 3] : 0.f;
    }
    *(float4*)&lds[c][p4] = v;
  }
  __syncthreads();

  // readout: thread (p_local = lane, c_oct = wave) covers 16 c of its pixel
  const int pl = tid & 63, co = tid >> 6;
  float ssq = 0.f;
  uint pk[8];
#pragma unroll
  for (int q = 0; q < 8; ++q) {
    float a = lds[co * 16 + q * 2 + 0][pl];
    float b = lds[co * 16 + q * 2 + 1][pl];
    ssq += a * a + b * b;
    pk[q] = pk2(a, b);
  }
  red[co][pl] = ssq;

  const size_t fbase = ((size_t)n * PTILES + pt) * 16;
#pragma unroll
  for (int o = 0; o < 2; ++o) {
    const int cg = c0 + co * 16 + o * 8;   // global c of this octet (j=0)
    const int ks  = cg >> 5;
    const int lhi = (cg >> 3) & 3;
    u32x4 wv;
    wv[0] = pk[o * 4 + 0]; wv[1] = pk[o * 4 + 1];
    wv[2] = pk[o * 4 + 2]; wv[3] = pk[o * 4 + 3];
    *(u32x4*)(xtf + (((fbase + ks) * 4 + lhi) * 64 + pl) * 8) = wv;
  }
  __syncthreads();
  if (tid < 64) {
    int p = p0 + tid;
    if (p < P_DIM)
      ssq_part[((size_t)ct * N_DIM + n) * P_DIM + p] =
          red[0][tid] + red[1][tid] + red[2][tid] + red[3][tid];
  }
}

// ---------------------------------------------------------------------------
// Kernel A (v7): logits GEMM from pre-transposed xtf + softmax.
// Inner loop = short8 load + MFMA only (no cvt/ssq VALU -- agg-style).
// invn from ssq_part table. Pixel mapping p = p0 + pt*16 + l15 (round-5
// proven C-layout). ks loop fully unrolled (rule #20: wfrag scratch).
// ---------------------------------------------------------------------------
__global__ __launch_bounds__(256, 2) void netvlad_assign(
    const float* __restrict__ w, const ushort* __restrict__ xtf,
    const float* __restrict__ ssq_part,
    ushort* __restrict__ a2, float* __restrict__ asum_part)
{
  const int n = blockIdx.y, bpt = blockIdx.x, p0 = bpt * 64;
  const int tid = threadIdx.x, wave = tid >> 6, lane = tid & 63;
  const int l15 = lane & 15, lhi = lane >> 4;

  __shared__ float invn_s[64];
  __shared__ float wredm[4][4][16];
  __shared__ float wreds[4][4][16];

  // ---- W fragment preload (fp32 -> bf16 regs), k-slot = ks*32 + lhi*8 + j
  short8 wfrag[16];
  const float* wrow = w + (size_t)(wave * 16 + l15) * C_DIM + lhi * 8;
#pragma unroll
  for (int ks = 0; ks < 16; ++ks) {
    f32x4 f0 = *(const f32x4*)(wrow + ks * 32);
    f32x4 f1 = *(const f32x4*)(wrow + ks * 32 + 4);
    u32x4 up;
    up[0] = pk2(f0[0], f0[1]); up[1] = pk2(f0[2], f0[3]);
    up[2] = pk2(f1[0], f1[1]); up[3] = pk2(f1[2], f1[3]);
    wfrag[ks] = __builtin_bit_cast(short8, up);
  }

  // ---- invn per pixel from ssq_part (8 ctile partials)
  if (tid < 64) {
    int p = p0 + tid;
    float s = 0.f;
    if (p < P_DIM) {
#pragma unroll
      for (int ct = 0; ct < CTILES; ++ct)
        s += ssq_part[((size_t)ct * N_DIM + n) * P_DIM + p];
    }
    invn_s[tid] = 1.0f / fmaxf(sqrtf(s), 1e-12f);
  }

  // ---- MFMA main loop: direct short8 fragment loads from xtf
  const ushort* xf_base = xtf + ((size_t)n * PTILES + bpt) * 16 * 4 * 64 * 8;
  f32x4 acc[4];
#pragma unroll
  for (int pt = 0; pt < 4; ++pt) acc[pt] = (f32x4){0.f, 0.f, 0.f, 0.f};

#pragma unroll
  for (int ks = 0; ks < 16; ++ks) {
#pragma unroll
    for (int pt = 0; pt < 4; ++pt) {
      short8 xf = *(const short8*)(xf_base
                    + (((size_t)ks * 4 + lhi) * 64 + pt * 16 + l15) * 8);
      acc[pt] = __builtin_amdgcn_mfma_f32_16x16x32_bf16(wfrag[ks], xf, acc[pt], 0, 0, 0);
    }
  }
  __syncthreads();   // invn_s ready

  // ---- softmax over k (64 values per pixel column, cross-wave via LDS)
  float linv[4], lg[4][4];
#pragma unroll
  for (int pt = 0; pt < 4; ++pt) {
    linv[pt] = invn_s[pt * 16 + l15];
    float m = -1e30f;
#pragma unroll
    for (int r = 0; r < 4; ++r) { lg[pt][r] = acc[pt][r] * linv[pt]; m = fmaxf(m, lg[pt][r]); }
    m = fmaxf(m, __shfl_xor(m, 16));
    m = fmaxf(m, __shfl_xor(m, 32));
    if (lhi == 0) wredm[wave][pt][l15] = m;
  }
  __syncthreads();
#pragma unroll
  for (int pt = 0; pt < 4; ++pt) {
    float m = fmaxf(fmaxf(wredm[0][pt][l15], wredm[1][pt][l15]),
                    fmaxf(wredm[2][pt][l15], wredm[3][pt][l15]));
    float s = 0.f;
#pragma unroll
    for (int r = 0; r < 4; ++r) { lg[pt][r] = __expf(lg[pt][r] - m); s += lg[pt][r]; }
    s += __shfl_xor(s, 16);
    s += __shfl_xor(s, 32);
    if (lhi == 0) wreds[wave][pt][l15] = s;
  }
  __syncthreads();

  ushort* a2b = a2 + (size_t)n * K_DIM * P_PAD;
  float asr[4] = {0.f, 0.f, 0.f, 0.f};
#pragma unroll
  for (int pt = 0; pt < 4; ++pt) {
    float stot = wreds[0][pt][l15] + wreds[1][pt][l15] +
                 wreds[2][pt][l15] + wreds[3][pt][l15];
    float rs = 1.0f / stot;
    int p = p0 + pt * 16 + l15;
    bool vv = p < P_DIM;
#pragma unroll
    for (int r = 0; r < 4; ++r) {
      float a = lg[pt][r] * rs;
      if (vv) asr[r] += a;
      if (p < P_PAD) {
        int k = wave * 16 + lhi * 4 + r;
        a2b[(size_t)k * P_PAD + p] = vv ? f2bf(a * linv[pt]) : (ushort)0;
      }
    }
  }
#pragma unroll
  for (int r = 0; r < 4; ++r) {
    float v = asr[r];
    v += __shfl_xor(v, 1); v += __shfl_xor(v, 2);
    v += __shfl_xor(v, 4); v += __shfl_xor(v, 8);
    if (l15 == 0) {
      int k = wave * 16 + lhi * 4 + r;
      asum_part[((size_t)n * K_DIM + k) * PTILES + bpt] = v;
    }
  }
}

// ---------------------------------------------------------------------------
// Kernel B: agg[n,k,c] = sum_p a2[k,p]*x[c,p] via MFMA (unchanged, ~5us).
// ---------------------------------------------------------------------------
__global__ __launch_bounds__(256, 4) void netvlad_agg(
    const float* __restrict__ x, const ushort* __restrict__ a2,
    const float* __restrict__ asum_part, const float* __restrict__ cent,
    float* __restrict__ out)
{
  const int n = blockIdx.y, ct = blockIdx.x, c0 = ct * 64;
  const int tid = threadIdx.x, wave = tid >> 6, lane = tid & 63;
  const int l15 = lane & 15, lhi = lane >> 4;

  __shared__ float asum_s[64];
  if (tid < 64) {
    const float* ap = asum_part + ((size_t)n * K_DIM + tid) * PTILES;
    float s = 0.f;
#pragma unroll
    for (int j = 0; j < PTILES; ++j) s += ap[j];
    asum_s[tid] = s;
  }
  __syncthreads();

  f32x4 acc[4];
#pragma unroll
  for (int mt = 0; mt < 4; ++mt) acc[mt] = (f32x4){0.f, 0.f, 0.f, 0.f};

  const float*  xrow = x + (size_t)n * C_DIM * P_DIM
                         + (size_t)(c0 + wave * 16 + l15) * P_DIM;
  const ushort* ab   = a2 + (size_t)n * K_DIM * P_PAD;

  for (int ks = 0; ks < 29; ++ks) {
    int pb = ks * 32 + lhi * 8;
    short8 bfrag;
    if (pb + 8 <= P_DIM) {
      f32x4 f0 = *(const f32x4*)(xrow + pb);
      f32x4 f1 = *(const f32x4*)(xrow + pb + 4);
      u32x4 up;
      up[0] = pk2(f0[0], f0[1]); up[1] = pk2(f0[2], f0[3]);
      up[2] = pk2(f1[0], f1[1]); up[3] = pk2(f1[2], f1[3]);
      bfrag = __builtin_bit_cast(short8, up);
    } else {
#pragma unroll
      for (int j = 0; j < 8; ++j)
        bfrag[j] = (pb + j < P_DIM) ? (short)f2bf(xrow[pb + j]) : (short)0;
    }
#pragma unroll
    for (int mt = 0; mt < 4; ++mt) {
      short8 afrag = *(const short8*)(ab + (size_t)(mt * 16 + l15) * P_PAD
                                         + ks * 32 + lhi * 8);
      acc[mt] = __builtin_amdgcn_mfma_f32_16x16x32_bf16(afrag, bfrag, acc[mt], 0, 0, 0);
    }
  }

  const int c = c0 + wave * 16 + l15;
#pragma unroll
  for (int mt = 0; mt < 4; ++mt) {
#pragma unroll
    for (int r = 0; r < 4; ++r) {
      int k = mt * 16 + lhi * 4 + r;
      out[((size_t)n * K_DIM + k) * C_DIM + c] =
          acc[mt][r] - asum_s[k] * cent[(size_t)k * C_DIM + c];
    }
  }
}

extern "C" void kernel_launch(void* const* d_in, const int* in_sizes, int n_in,
                              void* d_out, int out_size, void* d_ws, size_t ws_size,
                              hipStream_t stream) {
  const float* x    = (const float*)d_in[0];
  const float* w    = (const float*)d_in[1];
  const float* cent = (const float*)d_in[2];
  float* out = (float*)d_out;

  char* wsb = (char*)d_ws;
  ushort* a2        = (ushort*)wsb;
  float*  asum_part = (float*)(wsb + A2_ELEMS * sizeof(ushort));
  float*  ssq_part  = asum_part + ASUM_ELEMS;
  ushort* xtf       = (ushort*)((char*)(ssq_part + SSQ_ELEMS));

  transpose_x   <<<dim3(CTILES, PTILES, N_DIM), 256, 0, stream>>>(x, xtf, ssq_part);
  netvlad_assign<<<dim3(PTILES, N_DIM),         256, 0, stream>>>(w, xtf, ssq_part, a2, asum_part);
  netvlad_agg   <<<dim3(CTILES, N_DIM),         256, 0, stream>>>(x, a2, asum_part, cent, out);
}

// Round 15
// 83.909 us; speedup vs baseline: 1.0887x; 1.0887x over previous
//
#include <hip/hip_runtime.h>
#include <math.h>

#define N_DIM 64
#define C_DIM 512
#define K_DIM 64
#define P_DIM 900
#define P_PAD 928          // 29 * 32 (agg K-steps of 32)
#define PTILES 15          // assign p-blocks of 64

typedef __attribute__((ext_vector_type(8))) short short8;   // 8 bf16 = 4 VGPR
typedef __attribute__((ext_vector_type(4))) float f32x4;    // MFMA C/D + x loads
typedef __attribute__((ext_vector_type(4))) uint  u32x4;

#define A2_ELEMS   ((size_t)N_DIM * K_DIM * P_PAD)

// fp32 -> bf16 bits, round-to-nearest-even (inputs finite)
__device__ inline ushort f2bf(float f) {
  uint u = __builtin_bit_cast(uint, f);
  u += 0x7FFFu + ((u >> 16) & 1u);
  return (ushort)(u >> 16);
}
__device__ inline uint pk2(float a, float b) {
  return (uint)f2bf(a) | ((uint)f2bf(b) << 16);
}

// async global->LDS DMA, 16B per lane; LDS dest = wave-uniform base + lane*16
__device__ __forceinline__ void gload16(const float* g, float* lds_base) {
  __builtin_amdgcn_global_load_lds(
      (const __attribute__((address_space(1))) void*)g,
      (__attribute__((address_space(3))) void*)lds_base, 16, 0, 0);
}

// ---------------------------------------------------------------------------
// Kernel A (v8): logits GEMM via MFMA + fused L2-norm + softmax.
// x staged through LDS with ASYNC global_load_lds (deep DMA queue => HBM
// latency hidden without VGPR cost; round-12 analysis: direct loads were
// latency-bound at 1.24 TB/s because vmcnt(0) per ks-step capped in-flight
// bytes). m97-style 2-barrier double buffer: chunk = 32c x 64p fp32 (8 KB).
// Fragment read: ds_read_b128 at [row 8*lhi+j][col 4*l15] -- pixel mapping
// p = p0 + 4*l15 + pt (round-12 proven). ks loop fully unrolled (rule #20).
// ---------------------------------------------------------------------------
__global__ __launch_bounds__(256, 2) void netvlad_assign(
    const float* __restrict__ x, const float* __restrict__ w,
    ushort* __restrict__ a2, float* __restrict__ asum_part)
{
  const int n = blockIdx.y, bpt = blockIdx.x, p0 = bpt * 64;
  const int tid = threadIdx.x, wv = tid >> 6, lane = tid & 63;
  const int l15 = lane & 15, lhi = lane >> 4;

  __shared__ float xs[2][2048];       // 2 x 8 KB chunk buffers [32 c][64 p]
  __shared__ float wredm[4][4][16];
  __shared__ float wreds[4][4][16];

  // ---- W fragment preload (fp32 -> bf16 regs), k-slot = ks*32 + lhi*8 + j
  short8 wfrag[16];
  const float* wrow = w + (size_t)(wv * 16 + l15) * C_DIM + lhi * 8;
#pragma unroll
  for (int ks = 0; ks < 16; ++ks) {
    f32x4 f0 = *(const f32x4*)(wrow + ks * 32);
    f32x4 f1 = *(const f32x4*)(wrow + ks * 32 + 4);
    u32x4 up;
    up[0] = pk2(f0[0], f0[1]); up[1] = pk2(f0[2], f0[3]);
    up[2] = pk2(f1[0], f1[1]); up[3] = pk2(f1[2], f1[3]);
    wfrag[ks] = __builtin_bit_cast(short8, up);
  }

  // ---- staging geometry: lane -> (row rr = seg*4 + lane/16, 4 pixels)
  const float* xb = x + (size_t)n * C_DIM * P_DIM;
  int pld = p0 + (lane & 15) * 4;
  if (pld > P_DIM - 4) pld = P_DIM - 4;   // clamp (dup pixels, gated later)
  const int rquad = lane >> 4;            // row-within-segment

  // stage chunk ks into buffer b: 8 segments of 1 KB (wave wv does 2)
#define STAGE(b, ks)                                                          \
  {                                                                           \
    _Pragma("unroll")                                                         \
    for (int i = 0; i < 2; ++i) {                                             \
      int seg = wv + 4 * i;                                                   \
      int rr  = seg * 4 + rquad;                                              \
      gload16(xb + (size_t)((ks) * 32 + rr) * P_DIM + pld, &xs[b][seg * 256]);\
    }                                                                         \
  }

  f32x4 acc[4];
#pragma unroll
  for (int pt = 0; pt < 4; ++pt) acc[pt] = (f32x4){0.f, 0.f, 0.f, 0.f};
  float ssqp[4] = {0.f, 0.f, 0.f, 0.f};

  STAGE(0, 0);
#pragma unroll
  for (int ks = 0; ks < 16; ++ks) {
    if (ks + 1 < 16) STAGE((ks + 1) & 1, ks + 1);
    __syncthreads();                    // chunk ks staged (drain accepted)
    const float* buf = xs[ks & 1];
    f32x4 rd[8];
#pragma unroll
    for (int j = 0; j < 8; ++j)
      rd[j] = *(const f32x4*)&buf[(8 * lhi + j) * 64 + l15 * 4];
#pragma unroll
    for (int pt = 0; pt < 4; ++pt) {
      ssqp[pt] += rd[0][pt] * rd[0][pt] + rd[1][pt] * rd[1][pt]
                + rd[2][pt] * rd[2][pt] + rd[3][pt] * rd[3][pt]
                + rd[4][pt] * rd[4][pt] + rd[5][pt] * rd[5][pt]
                + rd[6][pt] * rd[6][pt] + rd[7][pt] * rd[7][pt];
      u32x4 up;
      up[0] = pk2(rd[0][pt], rd[1][pt]); up[1] = pk2(rd[2][pt], rd[3][pt]);
      up[2] = pk2(rd[4][pt], rd[5][pt]); up[3] = pk2(rd[6][pt], rd[7][pt]);
      short8 xf = __builtin_bit_cast(short8, up);
      acc[pt] = __builtin_amdgcn_mfma_f32_16x16x32_bf16(wfrag[ks], xf, acc[pt], 0, 0, 0);
    }
    __syncthreads();                    // reads done before buf reuse
  }
#undef STAGE

  // ---- invn per pixel: full ssq = sum over the 4 lhi octet-groups
  float linv[4];
#pragma unroll
  for (int pt = 0; pt < 4; ++pt) {
    float s = ssqp[pt];
    s += __shfl_xor(s, 16);
    s += __shfl_xor(s, 32);
    linv[pt] = 1.0f / fmaxf(sqrtf(s), 1e-12f);
  }

  // ---- softmax over k (64 values per pixel slot, cross-wave via LDS)
  float lg[4][4];
#pragma unroll
  for (int pt = 0; pt < 4; ++pt) {
    float m = -1e30f;
#pragma unroll
    for (int r = 0; r < 4; ++r) { lg[pt][r] = acc[pt][r] * linv[pt]; m = fmaxf(m, lg[pt][r]); }
    m = fmaxf(m, __shfl_xor(m, 16));
    m = fmaxf(m, __shfl_xor(m, 32));
    if (lhi == 0) wredm[wv][pt][l15] = m;
  }
  __syncthreads();
#pragma unroll
  for (int pt = 0; pt < 4; ++pt) {
    float m = fmaxf(fmaxf(wredm[0][pt][l15], wredm[1][pt][l15]),
                    fmaxf(wredm[2][pt][l15], wredm[3][pt][l15]));
    float s = 0.f;
#pragma unroll
    for (int r = 0; r < 4; ++r) { lg[pt][r] = __expf(lg[pt][r] - m); s += lg[pt][r]; }
    s += __shfl_xor(s, 16);
    s += __shfl_xor(s, 32);
    if (lhi == 0) wreds[wv][pt][l15] = s;
  }
  __syncthreads();

  ushort* a2b = a2 + (size_t)n * K_DIM * P_PAD;
  float asr[4] = {0.f, 0.f, 0.f, 0.f};
#pragma unroll
  for (int pt = 0; pt < 4; ++pt) {
    float stot = wreds[0][pt][l15] + wreds[1][pt][l15] +
                 wreds[2][pt][l15] + wreds[3][pt][l15];
    float rs = 1.0f / stot;
    int p = p0 + 4 * l15 + pt;          // vector-load pixel mapping
    bool vv = p < P_DIM;
#pragma unroll
    for (int r = 0; r < 4; ++r) {
      float a = lg[pt][r] * rs;
      if (vv) asr[r] += a;
      if (p < P_PAD) {
        int k = wv * 16 + lhi * 4 + r;
        a2b[(size_t)k * P_PAD + p] = vv ? f2bf(a * linv[pt]) : (ushort)0;
      }
    }
  }
#pragma unroll
  for (int r = 0; r < 4; ++r) {
    float v = asr[r];
    v += __shfl_xor(v, 1); v += __shfl_xor(v, 2);
    v += __shfl_xor(v, 4); v += __shfl_xor(v, 8);
    if (l15 == 0) {
      int k = wv * 16 + lhi * 4 + r;
      asum_part[((size_t)n * K_DIM + k) * PTILES + bpt] = v;
    }
  }
}

// ---------------------------------------------------------------------------
// Kernel B: agg[n,k,c] = sum_p a2[k,p]*x[c,p] via MFMA (A=a2, B=x direct from
// global -- L3-hot after assign). Fused epilogue: out = acc - asum*centroid.
// ---------------------------------------------------------------------------
__global__ __launch_bounds__(256, 4) void netvlad_agg(
    const float* __restrict__ x, const ushort* __restrict__ a2,
    const float* __restrict__ asum_part, const float* __restrict__ cent,
    float* __restrict__ out)
{
  const int n = blockIdx.y, ct = blockIdx.x, c0 = ct * 64;
  const int tid = threadIdx.x, wave = tid >> 6, lane = tid & 63;
  const int l15 = lane & 15, lhi = lane >> 4;

  __shared__ float asum_s[64];
  if (tid < 64) {
    const float* ap = asum_part + ((size_t)n * K_DIM + tid) * PTILES;
    float s = 0.f;
#pragma unroll
    for (int j = 0; j < PTILES; ++j) s += ap[j];
    asum_s[tid] = s;
  }
  __syncthreads();

  f32x4 acc[4];
#pragma unroll
  for (int mt = 0; mt < 4; ++mt) acc[mt] = (f32x4){0.f, 0.f, 0.f, 0.f};

  const float*  xrow = x + (size_t)n * C_DIM * P_DIM
                         + (size_t)(c0 + wave * 16 + l15) * P_DIM;
  const ushort* ab   = a2 + (size_t)n * K_DIM * P_PAD;

  for (int ks = 0; ks < 29; ++ks) {
    int pb = ks * 32 + lhi * 8;
    short8 bfrag;
    if (pb + 8 <= P_DIM) {
      f32x4 f0 = *(const f32x4*)(xrow + pb);
      f32x4 f1 = *(const f32x4*)(xrow + pb + 4);
      u32x4 up;
      up[0] = pk2(f0[0], f0[1]); up[1] = pk2(f0[2], f0[3]);
      up[2] = pk2(f1[0], f1[1]); up[3] = pk2(f1[2], f1[3]);
      bfrag = __builtin_bit_cast(short8, up);
    } else {
#pragma unroll
      for (int j = 0; j < 8; ++j)
        bfrag[j] = (pb + j < P_DIM) ? (short)f2bf(xrow[pb + j]) : (short)0;
    }
#pragma unroll
    for (int mt = 0; mt < 4; ++mt) {
      short8 afrag = *(const short8*)(ab + (size_t)(mt * 16 + l15) * P_PAD
                                         + ks * 32 + lhi * 8);
      acc[mt] = __builtin_amdgcn_mfma_f32_16x16x32_bf16(afrag, bfrag, acc[mt], 0, 0, 0);
    }
  }

  const int c = c0 + wave * 16 + l15;
#pragma unroll
  for (int mt = 0; mt < 4; ++mt) {
#pragma unroll
    for (int r = 0; r < 4; ++r) {
      int k = mt * 16 + lhi * 4 + r;
      out[((size_t)n * K_DIM + k) * C_DIM + c] =
          acc[mt][r] - asum_s[k] * cent[(size_t)k * C_DIM + c];
    }
  }
}

extern "C" void kernel_launch(void* const* d_in, const int* in_sizes, int n_in,
                              void* d_out, int out_size, void* d_ws, size_t ws_size,
                              hipStream_t stream) {
  const float* x    = (const float*)d_in[0];
  const float* w    = (const float*)d_in[1];
  const float* cent = (const float*)d_in[2];
  float* out = (float*)d_out;

  ushort* a2        = (ushort*)d_ws;
  float*  asum_part = (float*)((char*)d_ws + A2_ELEMS * sizeof(ushort));

  netvlad_assign<<<dim3(PTILES, N_DIM), 256, 0, stream>>>(x, w, a2, asum_part);
  netvlad_agg   <<<dim3(8, N_DIM),      256, 0, stream>>>(x, a2, asum_part, cent, out);
}